// Round 5
// baseline (131.785 us; speedup 1.0000x reference)
//
#include <hip/hip_runtime.h>
#include <math.h>

#define B_   4
#define K_   200
#define DIM_ 256
#define T_   800

#define S_UP 68    // prep reduce-scratch stride
#define S_O  66    // main partial-row stride (pad 2: ~2-way banks max)
#define KP_  204   // W8 row stride (16B-aligned, covers K_=200)

__device__ __forceinline__ float silu_f(float x) {
    return x / (1.0f + __expf(-x));
}
__device__ __forceinline__ void fma4(float4& a, float s, const float4& v) {
    a.x = fmaf(s, v.x, a.x); a.y = fmaf(s, v.y, a.y);
    a.z = fmaf(s, v.z, a.z); a.w = fmaf(s, v.w, a.w);
}

// ---------------------------------------------------------------------------
// Prep (unchanged from R4): conv + scan + const folding.
// cw[b][j][k]: j=0 beta0, j=1 beta1, j=2..17 B_j  (SoA, k-fastest).
// Grid (50, B_), 256 threads.
// ---------------------------------------------------------------------------
__global__ __launch_bounds__(256) void prep_kernel(
        const float* __restrict__ dur,
        const float* __restrict__ feats,
        const float* __restrict__ c1w, const float* __restrict__ c1b,
        const float* __restrict__ c2w, const float* __restrict__ c2b,
        const float* __restrict__ sw1_w1, const float* __restrict__ sw1_b1,
        const float* __restrict__ sw2_w1, const float* __restrict__ sw2_b1,
        float* __restrict__ cw) {
    const int b = blockIdx.y, k0 = blockIdx.x * 4;
    const int tid = threadIdx.x, w = tid >> 6, l = tid & 63;

    __shared__ float wT[16][772];
    __shared__ float red[64][S_UP];
    __shared__ float sSc[K_], sEc[K_];
    __shared__ float sfeat[4][16];

    for (int i = tid; i < 3 * DIM_ * 8; i += 256) {
        int tc = i >> 3, o = i & 7;
        wT[o][tc]     = c1w[i];
        wT[8 + o][tc] = c2w[i];
    }
    if (tid < 64) {
        float4 dv = make_float4(0.f, 0.f, 0.f, 0.f);
        if (tid < 50) dv = *(const float4*)&dur[b * K_ + tid * 4];
        float s0 = dv.x, s1 = s0 + dv.y, s2 = s1 + dv.z, s3 = s2 + dv.w;
        float sc = s3;
#pragma unroll
        for (int off = 1; off < 64; off <<= 1) {
            float v = __shfl_up(sc, off);
            if (tid >= off) sc += v;
        }
        float excl = sc - s3;
        if (tid < 50) {
            *(float4*)&sSc[tid * 4] = make_float4(excl, excl + s0, excl + s1, excl + s2);
            *(float4*)&sEc[tid * 4] = make_float4(excl + s0, excl + s1, excl + s2, excl + s3);
        }
    }
    __syncthreads();

    {
        const int k = k0 + w;
        const float4* f4 = (const float4*)feats;
        float4 fv[3];
#pragma unroll
        for (int tap = 0; tap < 3; ++tap) {
            int kk = k - 1 + tap;
            bool valid = (kk >= 0 && kk < K_);
            int kc = valid ? kk : 0;
            float4 v = f4[(size_t)(b * K_ + kc) * 64 + l];
            fv[tap] = valid ? v : make_float4(0.f, 0.f, 0.f, 0.f);
        }
        float acc[16];
#pragma unroll
        for (int oc = 0; oc < 16; ++oc) acc[oc] = 0.f;
#pragma unroll
        for (int tap = 0; tap < 3; ++tap) {
#pragma unroll
            for (int oc = 0; oc < 16; ++oc) {
                float4 wv = *(const float4*)&wT[oc][tap * DIM_ + 4 * l];
                acc[oc] += fv[tap].x * wv.x + fv[tap].y * wv.y
                         + fv[tap].z * wv.z + fv[tap].w * wv.w;
            }
        }
#pragma unroll
        for (int oc = 0; oc < 16; ++oc) red[w * 16 + oc][l] = acc[oc];
    }
    __syncthreads();
    {
        const int rwv = tid >> 6, oc = (tid >> 2) & 15, rq = tid & 3;
        const float* base = &red[rwv * 16 + oc][rq * 16];
        float4 b0 = *(const float4*)&base[0];
        float4 b1 = *(const float4*)&base[4];
        float4 b2 = *(const float4*)&base[8];
        float4 b3 = *(const float4*)&base[12];
        float s = b0.x + b0.y + b0.z + b0.w + b1.x + b1.y + b1.z + b1.w
                + b2.x + b2.y + b2.z + b2.w + b3.x + b3.y + b3.z + b3.w;
        s += __shfl_down(s, 1);
        s += __shfl_down(s, 2);
        if (rq == 0) {
            float bias = (oc < 8) ? c1b[oc] : c2b[oc & 7];
            sfeat[rwv][oc] = silu_f(s + bias);
        }
    }
    __syncthreads();

    if (tid < 64) {
        const int j = tid >> 2, klc = tid & 3, kk = k0 + klc;
        float st = sSc[kk], en = sEc[kk];
        float a = sw1_b1[j] - st * sw1_w1[j] + en * sw1_w1[16 + j];
#pragma unroll
        for (int i = 0; i < 8; ++i) a += sfeat[klc][i] * sw1_w1[(2 + i) * 16 + j];
        cw[(b * 18 + 2 + j) * K_ + kk] = a;
    } else if (tid < 72) {
        const int idx = tid - 64, which = idx >> 2, klc = idx & 3, kk = k0 + klc;
        float st = sSc[kk], en = sEc[kk];
        float a = sw2_b1[which] - st * sw2_w1[which] + en * sw2_w1[2 + which];
#pragma unroll
        for (int i = 0; i < 8; ++i) a += sfeat[klc][8 + i] * sw2_w1[(2 + i) * 2 + which];
        cw[(b * 18 + which) * K_ + kk] = a;
    }
}

// ---------------------------------------------------------------------------
// Main: 8 frames/block, 512 threads (wave w <-> frame t0+w). Grid (100, B).
// Lane l owns k = 4l..4l+3 (l<50).  Phase 3: wave w covers k in [25w,25w+25),
// frames processed in two halves of 4 to bound LDS.
// ---------------------------------------------------------------------------
__global__ __launch_bounds__(512, 4) void main_kernel(
        const float* __restrict__ feats,
        const float* __restrict__ cw,
        const float* __restrict__ sw1_w1, const float* __restrict__ sw1_w2,
        const float* __restrict__ sw1_b2,
        const float* __restrict__ sw2_w1, const float* __restrict__ sw2_w2,
        const float* __restrict__ sw2_b2,
        const float* __restrict__ p1_w,   const float* __restrict__ p1_b,
        const float* __restrict__ p2_w,   const float* __restrict__ p2_b,
        float* __restrict__ out) {
    const int t0 = blockIdx.x * 8, b = blockIdx.y;
    const int tid = threadIdx.x, w = tid >> 6, l = tid & 63;
    const float tf = (float)(t0 + w);

    __shared__ alignas(16) float upool[128 * S_O];  // A rows / O-partial rows
    __shared__ alignas(16) float W8[8][KP_];        // softmax wgt, frame-major
    __shared__ alignas(16) float At[16][8];         // A[p][frame]
    __shared__ alignas(16) float lw2R[256];         // sw1_w2 row-major
    __shared__ alignas(16) float lb2s[16];

    if (tid < 256) lw2R[tid] = sw1_w2[tid];
    if (tid < 16) lb2s[tid] = sw1_b2[tid];

    const int  kbase = (l < 50) ? 4 * l : 196;
    const bool kv    = (l < 50);
    const float* cbg = cw + b * 18 * K_;

    // coalesced b128 const loads
    float4 c0v = *(const float4*)&cbg[kbase];
    float4 c1v = *(const float4*)&cbg[K_ + kbase];
    float4 Bcur[4], Bnxt[4];
#pragma unroll
    for (int j = 0; j < 4; ++j) Bcur[j] = *(const float4*)&cbg[(2 + j) * K_ + kbase];

    __syncthreads();   // b0: lw2R/lb2s staged

    // ---- phase 1: logits + wave softmax ----
    const float a0 = sw2_w1[0] - sw2_w1[2], a1 = sw2_w1[1] - sw2_w1[3];
    const float rw20 = sw2_w2[0], rw21 = sw2_w2[1], rw22 = sw2_w2[2], rw23 = sw2_w2[3];
    const float rb20 = sw2_b2[0], rb21 = sw2_b2[1];
    const float p10 = p1_w[0], p11 = p1_w[1], p1b0 = p1_b[0];

    float lg[4];
    {
        float c0a[4] = { c0v.x, c0v.y, c0v.z, c0v.w };
        float c1a[4] = { c1v.x, c1v.y, c1v.z, c1v.w };
#pragma unroll
        for (int i = 0; i < 4; ++i) {
            float h0 = silu_f(fmaf(a0, tf, c0a[i]));
            float h1 = silu_f(fmaf(a1, tf, c1a[i]));
            float g0 = silu_f(rb20 + h0 * rw20 + h1 * rw22);
            float g1 = silu_f(rb21 + h0 * rw21 + h1 * rw23);
            lg[i] = kv ? (g0 * p10 + g1 * p11 + p1b0) : -1e30f;
        }
    }
    float m = fmaxf(fmaxf(lg[0], lg[1]), fmaxf(lg[2], lg[3]));
#pragma unroll
    for (int off = 32; off > 0; off >>= 1) m = fmaxf(m, __shfl_xor(m, off));
    float e0 = __expf(lg[0] - m), e1 = __expf(lg[1] - m);
    float e2 = __expf(lg[2] - m), e3 = __expf(lg[3] - m);
    float ssum = e0 + e1 + e2 + e3;
#pragma unroll
    for (int off = 32; off > 0; off >>= 1) ssum += __shfl_xor(ssum, off);
    float inv = 1.0f / ssum;
    float wgt[4] = { e0 * inv, e1 * inv, e2 * inv, e3 * inv };
    if (kv) *(float4*)&W8[w][kbase] = make_float4(wgt[0], wgt[1], wgt[2], wgt[3]);

    // prefetch first two phase-3 feats tiles
    const int kb = 25 * w;
    const float4* fB4 = (const float4*)(feats + (size_t)b * K_ * DIM_);
    float4 pf0 = fB4[(size_t)kb * 64 + l];
    float4 pf1 = fB4[(size_t)(kb + 1) * 64 + l];

    // ---- phase 2: cacc[i][j2] = h[i][:] @ w2  (streamed quarters) ----
    float4 cacc[4][4];
#pragma unroll
    for (int i = 0; i < 4; ++i)
#pragma unroll
        for (int q = 0; q < 4; ++q) cacc[i][q] = make_float4(0.f, 0.f, 0.f, 0.f);

#pragma unroll
    for (int grp = 0; grp < 4; ++grp) {
        if (grp < 3) {
#pragma unroll
            for (int j = 0; j < 4; ++j)
                Bnxt[j] = *(const float4*)&cbg[(2 + grp * 4 + 4 + j) * K_ + kbase];
        }
#pragma unroll
        for (int j = 0; j < 4; ++j) {
            const int jj = grp * 4 + j;
            float aj = (sw1_w1[jj] - sw1_w1[16 + jj]) * tf;
            float h0 = silu_f(aj + Bcur[j].x);
            float h1 = silu_f(aj + Bcur[j].y);
            float h2 = silu_f(aj + Bcur[j].z);
            float h3 = silu_f(aj + Bcur[j].w);
#pragma unroll
            for (int q = 0; q < 4; ++q) {
                float4 wv = *(const float4*)&lw2R[jj * 16 + 4 * q];
                fma4(cacc[0][q], h0, wv);
                fma4(cacc[1][q], h1, wv);
                fma4(cacc[2][q], h2, wv);
                fma4(cacc[3][q], h3, wv);
            }
        }
#pragma unroll
        for (int j = 0; j < 4; ++j) Bcur[j] = Bnxt[j];
    }
    // epilogue: acc[j2] = sum_i wgt[i]*silu(cacc+bias) -> A rows
#pragma unroll
    for (int q = 0; q < 4; ++q) {
        float4 bb = *(const float4*)&lb2s[4 * q];
        float sx = wgt[0] * silu_f(cacc[0][q].x + bb.x) + wgt[1] * silu_f(cacc[1][q].x + bb.x)
                 + wgt[2] * silu_f(cacc[2][q].x + bb.x) + wgt[3] * silu_f(cacc[3][q].x + bb.x);
        float sy = wgt[0] * silu_f(cacc[0][q].y + bb.y) + wgt[1] * silu_f(cacc[1][q].y + bb.y)
                 + wgt[2] * silu_f(cacc[2][q].y + bb.y) + wgt[3] * silu_f(cacc[3][q].y + bb.y);
        float sz = wgt[0] * silu_f(cacc[0][q].z + bb.z) + wgt[1] * silu_f(cacc[1][q].z + bb.z)
                 + wgt[2] * silu_f(cacc[2][q].z + bb.z) + wgt[3] * silu_f(cacc[3][q].z + bb.z);
        float sw = wgt[0] * silu_f(cacc[0][q].w + bb.w) + wgt[1] * silu_f(cacc[1][q].w + bb.w)
                 + wgt[2] * silu_f(cacc[2][q].w + bb.w) + wgt[3] * silu_f(cacc[3][q].w + bb.w);
        upool[(w * 16 + 4 * q + 0) * S_O + l] = sx;
        upool[(w * 16 + 4 * q + 1) * S_O + l] = sy;
        upool[(w * 16 + 4 * q + 2) * S_O + l] = sz;
        upool[(w * 16 + 4 * q + 3) * S_O + l] = sw;
    }
    // wave-local A reduce (same-wave LDS RAW, no barrier needed)
    {
        const int rj = (l >> 2) & 15, rq = l & 3;
        const float* base = &upool[(w * 16 + rj) * S_O + rq * 16];
        float4 b0 = *(const float4*)&base[0];
        float4 b1 = *(const float4*)&base[4];
        float4 b2 = *(const float4*)&base[8];
        float4 b3 = *(const float4*)&base[12];
        float s = b0.x + b0.y + b0.z + b0.w + b1.x + b1.y + b1.z + b1.w
                + b2.x + b2.y + b2.z + b2.w + b3.x + b3.y + b3.z + b3.w;
        s += __shfl_down(s, 1);
        s += __shfl_down(s, 2);
        if (rq == 0) At[rj][w] = s;
    }
    __syncthreads();   // b1: W8 + At ready, A rows free

    // ---- phase 3 + final, two frame-halves ----
    const int d = tid & 255, f0 = tid >> 8;
    const int l0 = d >> 2, qq = d & 3;

#pragma unroll
    for (int half = 0; half < 2; ++half) {
        float4 po[4];
#pragma unroll
        for (int f = 0; f < 4; ++f) po[f] = make_float4(0.f, 0.f, 0.f, 0.f);
        const float* Wr0 = W8[half * 4 + 0];
        const float* Wr1 = W8[half * 4 + 1];
        const float* Wr2 = W8[half * 4 + 2];
        const float* Wr3 = W8[half * 4 + 3];
#pragma unroll 5
        for (int kk = 0; kk < 25; ++kk) {
            const int k = kb + kk;
            float4 fv;
            if (half == 0 && kk == 0)      fv = pf0;
            else if (half == 0 && kk == 1) fv = pf1;
            else                           fv = fB4[(size_t)k * 64 + l];
            float w0 = Wr0[k], w1 = Wr1[k], w2 = Wr2[k], w3 = Wr3[k];
            fma4(po[0], w0, fv);
            fma4(po[1], w1, fv);
            fma4(po[2], w2, fv);
            fma4(po[3], w3, fv);
        }
#pragma unroll
        for (int f = 0; f < 4; ++f) {
            upool[(w * 16 + f * 4 + 0) * S_O + l] = po[f].x;
            upool[(w * 16 + f * 4 + 1) * S_O + l] = po[f].y;
            upool[(w * 16 + f * 4 + 2) * S_O + l] = po[f].z;
            upool[(w * 16 + f * 4 + 3) * S_O + l] = po[f].w;
        }
        __syncthreads();   // O-partials of this half ready

        // final: thread d, frames half*4 + {f0, f0+2}
#pragma unroll
        for (int ffi = 0; ffi < 2; ++ffi) {
            const int fr = f0 + 2 * ffi;
            float v = p2_b[d];
#pragma unroll
            for (int ww = 0; ww < 8; ++ww)
                v += upool[(ww * 16 + fr * 4 + qq) * S_O + l0];
#pragma unroll
            for (int p = 0; p < 16; ++p)
                v += At[p][half * 4 + fr] * p2_w[p * DIM_ + d];
            out[((size_t)b * T_ + t0 + half * 4 + fr) * DIM_ + d] = v;
        }
        if (half == 0) __syncthreads();   // rows reusable for half 1
    }
}

// ---------------------------------------------------------------------------
extern "C" void kernel_launch(void* const* d_in, const int* in_sizes, int n_in,
                              void* d_out, int out_size, void* d_ws, size_t ws_size,
                              hipStream_t stream) {
    const float* durations = (const float*)d_in[1];
    const float* features  = (const float*)d_in[2];
    const float* conv1_w   = (const float*)d_in[3];
    const float* conv1_b   = (const float*)d_in[4];
    const float* conv2_w   = (const float*)d_in[5];
    const float* conv2_b   = (const float*)d_in[6];
    const float* sw1_w1    = (const float*)d_in[7];
    const float* sw1_b1    = (const float*)d_in[8];
    const float* sw1_w2    = (const float*)d_in[9];
    const float* sw1_b2    = (const float*)d_in[10];
    const float* sw2_w1    = (const float*)d_in[11];
    const float* sw2_b1    = (const float*)d_in[12];
    const float* sw2_w2    = (const float*)d_in[13];
    const float* sw2_b2    = (const float*)d_in[14];
    const float* p1_w      = (const float*)d_in[15];
    const float* p1_b      = (const float*)d_in[16];
    const float* p2_w      = (const float*)d_in[17];
    const float* p2_b      = (const float*)d_in[18];
    float* out = (float*)d_out;

    float* cw = (float*)d_ws;   // [B][18][K]

    prep_kernel<<<dim3(50, B_), 256, 0, stream>>>(
        durations, features, conv1_w, conv1_b, conv2_w, conv2_b,
        sw1_w1, sw1_b1, sw2_w1, sw2_b1, cw);
    main_kernel<<<dim3(T_ / 8, B_), 512, 0, stream>>>(
        features, cw,
        sw1_w1, sw1_w2, sw1_b2,
        sw2_w1, sw2_w2, sw2_b2,
        p1_w, p1_b, p2_w, p2_b, out);
}